// Round 5
// baseline (597.089 us; speedup 1.0000x reference)
//
#include <hip/hip_runtime.h>
#include <hip/hip_cooperative_groups.h>
#include <math.h>

namespace cg = cooperative_groups;

#define NROWS 4096
#define NCOLS 16384
#define NGRP  512                   // NCOLS / 32
#define TOTAL_ELEMS (67108864ULL)   // NROWS * NCOLS
#define TOTAL4      (16777216ULL)   // TOTAL_ELEMS / 4
#define BLOCK 256

typedef float nfloat4 __attribute__((ext_vector_type(4)));  // native vec for nt-store

// Key invariant: grid stride (in float4 units) is a multiple of 4096 (one
// row of 16384 floats) for both 1024- and 2048-block grids, so each
// thread's group index g = (tid0 & 4095) >> 3 is LOOP-INVARIANT.

__global__ void init_kernel(unsigned int* __restrict__ gmax) {
    gmax[threadIdx.x] = 0u;   // 512 threads, 1 block (gmax lives in d_ws)
}

__device__ __forceinline__ float absmax4(float4 v) {
    return fmaxf(fmaxf(fabsf(v.x), fabsf(v.y)), fmaxf(fabsf(v.z), fabsf(v.w)));
}

__device__ __forceinline__ float quant1(float a, float s, float inv, float ee) {
    float r  = fminf(fabsf(a) * inv, 1.f);        // clip(|w|/s,0,1) — exact mul
    float sh = fminf(fmaxf(r + ee, 0.f), 1.f);    // clip(+eps_eff, 0, 1)
    float mq = rintf(sh * 8.f) * 0.125f;          // round-half-even = np.round
    float q  = copysignf(s * mq, a);
    return (a == 0.f) ? 0.f : q;                  // jnp.sign(0) == 0
}

// Single cooperative kernel. Phase A: per-group max|w|, 4 loads in flight,
// 8-lane shfl cluster reduce, ONE global atomic per cluster (no LDS stage —
// same atomic count, fewer barriers). grid.sync(). Phase B: derive group
// params per-thread, quantize with 4 independent load→quant→nt-store
// chains, descending sweep so the L3-freshest lines are re-read first
// (R4 profile: FETCH ≈ 1× weight ⇒ phase-B read is ~all Infinity-Cache hits).
__global__ void __launch_bounds__(BLOCK, 8)
fused_kernel(const float4* __restrict__ w,
             const float* __restrict__ eps_param,
             const float* __restrict__ delta,
             unsigned int* __restrict__ gmax,
             float* __restrict__ tail,
             float4* __restrict__ out) {
    const size_t tid0   = (size_t)blockIdx.x * BLOCK + threadIdx.x;
    const size_t stride = (size_t)gridDim.x * BLOCK;   // ≡ 0 mod 4096
    const int g = (int)((tid0 & 4095) >> 3);           // loop-invariant

    // ---- phase A: max|w|, 4 outstanding loads per thread ----
    float m0 = 0.f, m1 = 0.f, m2 = 0.f, m3 = 0.f;
    for (size_t i = tid0; i < TOTAL4; i += 4 * stride) {   // iters % 4 == 0
        float4 a = w[i];
        float4 b = w[i + stride];
        float4 c = w[i + 2 * stride];
        float4 d = w[i + 3 * stride];
        m0 = fmaxf(m0, absmax4(a));
        m1 = fmaxf(m1, absmax4(b));
        m2 = fmaxf(m2, absmax4(c));
        m3 = fmaxf(m3, absmax4(d));
    }
    float m = fmaxf(fmaxf(m0, m1), fmaxf(m2, m3));
    // 8 consecutive lanes share g (blocks are 256-aligned in tid)
    m = fmaxf(m, __shfl_xor(m, 1, 64));
    m = fmaxf(m, __shfl_xor(m, 2, 64));
    m = fmaxf(m, __shfl_xor(m, 4, 64));
    if ((threadIdx.x & 7) == 0)
        atomicMax(&gmax[g], __float_as_uint(m));   // device-scope by default

    cg::this_grid().sync();

    // ---- phase B: derive group params, write tail, quantize ----
    unsigned mb = __hip_atomic_load(&gmax[g], __ATOMIC_RELAXED,
                                    __HIP_MEMORY_SCOPE_AGENT);
    float ma = __uint_as_float(mb);
    float e = 0.f;
    if (ma > 0.f) {
        int ex;
        (void)frexpf(ma, &ex);      // ma = m * 2^ex, m in [0.5, 1)
        e = (float)(ex - 1);        // floor(log2(ma)) exactly
    }
    float eps = 0.5f * tanhf(eps_param[g]);
    float ee  = fminf(fmaxf(eps + delta[g], -0.5f), 0.5f);
    const int   ei  = (int)e;
    const float s   = __uint_as_float((unsigned)(ei + 127) << 23);  // 2^e
    const float inv = __uint_as_float((unsigned)(127 - ei) << 23);  // 2^-e

    // one writer per group lives in the first 16 blocks
    if (tid0 < 4096 && (tid0 & 7) == 0) {
        tail[g]        = ee;    // output: eps_eff
        tail[NGRP + g] = e;     // output: e_base
    }

    // Descending sweep, 4 independent load→quant→store chains per step.
    for (size_t ii = 4 * stride; ii <= TOTAL4; ii += 4 * stride) {
        size_t base = (TOTAL4 - ii) + tid0;
        float4 a = w[base];
        float4 b = w[base + stride];
        float4 c = w[base + 2 * stride];
        float4 d = w[base + 3 * stride];
        nfloat4 oa, ob, oc, od;
        oa.x = quant1(a.x, s, inv, ee); oa.y = quant1(a.y, s, inv, ee);
        oa.z = quant1(a.z, s, inv, ee); oa.w = quant1(a.w, s, inv, ee);
        __builtin_nontemporal_store(oa, (nfloat4*)&out[base]);
        ob.x = quant1(b.x, s, inv, ee); ob.y = quant1(b.y, s, inv, ee);
        ob.z = quant1(b.z, s, inv, ee); ob.w = quant1(b.w, s, inv, ee);
        __builtin_nontemporal_store(ob, (nfloat4*)&out[base + stride]);
        oc.x = quant1(c.x, s, inv, ee); oc.y = quant1(c.y, s, inv, ee);
        oc.z = quant1(c.z, s, inv, ee); oc.w = quant1(c.w, s, inv, ee);
        __builtin_nontemporal_store(oc, (nfloat4*)&out[base + 2 * stride]);
        od.x = quant1(d.x, s, inv, ee); od.y = quant1(d.y, s, inv, ee);
        od.z = quant1(d.z, s, inv, ee); od.w = quant1(d.w, s, inv, ee);
        __builtin_nontemporal_store(od, (nfloat4*)&out[base + 3 * stride]);
    }
}

extern "C" void kernel_launch(void* const* d_in, const int* in_sizes, int n_in,
                              void* d_out, int out_size, void* d_ws, size_t ws_size,
                              hipStream_t stream) {
    const float4* w4       = (const float4*)d_in[0];
    const float* eps_param = (const float*)d_in[1];
    const float* delta     = (const float*)d_in[2];
    float* out  = (float*)d_out;
    float* tail = out + TOTAL_ELEMS;            // 1024 floats: eps_eff + e_base
    unsigned int* gmax = (unsigned int*)d_ws;   // 512 uints of scratch
    float4* out4 = (float4*)out;

    // Pick the largest co-residency-safe grid (queried once; host-only calls,
    // graph-capture safe). 2048 blocks = 8/CU = 32 waves/CU if it fits.
    static int nblk = 0;
    if (nblk == 0) {
        int occ = 0;
        hipOccupancyMaxActiveBlocksPerMultiprocessor(&occ, fused_kernel, BLOCK, 0);
        int ncu = 0;
        hipDeviceGetAttribute(&ncu, hipDeviceAttributeMultiprocessorCount, 0);
        if (ncu <= 0) ncu = 256;
        nblk = (occ * ncu >= 2048) ? 2048 : 1024;   // both keep stride ≡ 0 mod 4096
    }

    init_kernel<<<1, NGRP, 0, stream>>>(gmax);

    void* args[] = { (void*)&w4, (void*)&eps_param, (void*)&delta,
                     (void*)&gmax, (void*)&tail, (void*)&out4 };
    hipLaunchCooperativeKernel((const void*)fused_kernel,
                               dim3(nblk), dim3(BLOCK),
                               args, 0, stream);
}

// Round 7
// 479.375 us; speedup vs baseline: 1.2456x; 1.2456x over previous
//
#include <hip/hip_runtime.h>
#include <math.h>

#define NROWS 4096
#define NCOLS 16384
#define NGRP  512                   // NCOLS / 32
#define TOTAL_ELEMS (67108864ULL)   // NROWS * NCOLS
#define TOTAL4      (16777216ULL)   // TOTAL_ELEMS / 4

typedef float nfloat4 __attribute__((ext_vector_type(4)));  // native vec for nt-store

// Key invariant: grid strides are multiples of 4096 float4s (one row of
// 16384 floats), so each thread's group index g = (tid0 & 4095) >> 3 is
// LOOP-INVARIANT.

__global__ void init_kernel(unsigned int* __restrict__ gmax) {
    gmax[threadIdx.x] = 0u;   // 512 threads, 1 block (gmax lives in d_ws)
}

__device__ __forceinline__ float absmax4(float4 v) {
    return fmaxf(fmaxf(fabsf(v.x), fabsf(v.y)), fmaxf(fabsf(v.z), fabsf(v.w)));
}

// Pass 1: per-group max(|w|). 4 independent load chains per thread
// (TOTAL4 / stride = 32 iters = 8 outer x 4-deep, exact). Private max →
// 8-lane shfl cluster reduce → LDS atomic → per-block flush (~32 nonzero
// groups per block).
__global__ void __launch_bounds__(256)
maxabs_kernel(const float4* __restrict__ w,
              unsigned int* __restrict__ gmax) {
    __shared__ unsigned int smax[NGRP];
    for (int i = threadIdx.x; i < NGRP; i += blockDim.x) smax[i] = 0u;
    __syncthreads();

    const size_t tid0   = (size_t)blockIdx.x * blockDim.x + threadIdx.x;
    const size_t stride = (size_t)gridDim.x * blockDim.x;   // 524288 ≡ 0 mod 4096
    const int g = (int)((tid0 & 4095) >> 3);                // loop-invariant

    float m0 = 0.f, m1 = 0.f, m2 = 0.f, m3 = 0.f;
    for (size_t i = tid0; i < TOTAL4; i += 4 * stride) {    // 8 outer iters
        float4 a = w[i];
        float4 b = w[i + stride];
        float4 c = w[i + 2 * stride];
        float4 d = w[i + 3 * stride];
        m0 = fmaxf(m0, absmax4(a));
        m1 = fmaxf(m1, absmax4(b));
        m2 = fmaxf(m2, absmax4(c));
        m3 = fmaxf(m3, absmax4(d));
    }
    float m = fmaxf(fmaxf(m0, m1), fmaxf(m2, m3));

    // 8 consecutive lanes share g (blocks are 256-aligned in tid)
    m = fmaxf(m, __shfl_xor(m, 1, 64));
    m = fmaxf(m, __shfl_xor(m, 2, 64));
    m = fmaxf(m, __shfl_xor(m, 4, 64));
    if ((threadIdx.x & 7) == 0)
        atomicMax(&smax[g], __float_as_uint(m));

    __syncthreads();
    for (int j = threadIdx.x; j < NGRP; j += blockDim.x)
        if (smax[j]) atomicMax(&gmax[j], smax[j]);
}

__device__ __forceinline__ float quant1(float a, float s, float inv, float ee) {
    float r  = fminf(fabsf(a) * inv, 1.f);        // clip(|w|/s,0,1) — exact mul
    float sh = fminf(fmaxf(r + ee, 0.f), 1.f);    // clip(+eps_eff, 0, 1)
    float mq = rintf(sh * 8.f) * 0.125f;          // round-half-even = np.round
    float q  = copysignf(s * mq, a);
    return (a == 0.f) ? 0.f : q;                  // jnp.sign(0) == 0
}

// Pass 2 (fused setup + quant): derive (ee, s, inv) per-thread for the
// loop-invariant group; 512 designated threads write the eps_eff / e_base
// output tail. Descending sweep (L3-freshest lines first — R4 profile
// confirmed the re-read is ~all Infinity-Cache hits), 4 independent
// load→quant→nt-store chains per outer step (8 iters = 2 outer x 4-deep).
__global__ void __launch_bounds__(256)
quant_kernel(const float4* __restrict__ w,
             const float* __restrict__ eps_param,
             const float* __restrict__ delta,
             const unsigned int* __restrict__ gmax,
             float* __restrict__ tail,
             float4* __restrict__ out) {
    const size_t tid0   = (size_t)blockIdx.x * blockDim.x + threadIdx.x;
    const size_t stride = (size_t)gridDim.x * blockDim.x;   // 2097152 ≡ 0 mod 4096
    const int g = (int)((tid0 & 4095) >> 3);                // loop-invariant

    float ma = __uint_as_float(gmax[g]);
    float e = 0.f;
    if (ma > 0.f) {
        int ex;
        (void)frexpf(ma, &ex);      // ma = m * 2^ex, m in [0.5, 1)
        e = (float)(ex - 1);        // floor(log2(ma)) exactly
    }
    float eps = 0.5f * tanhf(eps_param[g]);
    float ee  = fminf(fmaxf(eps + delta[g], -0.5f), 0.5f);
    const int   ei  = (int)e;
    const float s   = __uint_as_float((unsigned)(ei + 127) << 23);  // 2^e
    const float inv = __uint_as_float((unsigned)(127 - ei) << 23);  // 2^-e

    // one writer per group lives in the first 16 blocks
    if (tid0 < 4096 && (tid0 & 7) == 0) {
        tail[g]        = ee;    // output: eps_eff
        tail[NGRP + g] = e;     // output: e_base
    }

    // 2 outer iterations (descending), 4 chains each: slots k*4+{0,1,2,3}.
    #pragma unroll
    for (int k = 1; k >= 0; --k) {
        size_t base = tid0 + (size_t)k * 4 * stride;
        float4 a = w[base];
        float4 b = w[base + stride];
        float4 c = w[base + 2 * stride];
        float4 d = w[base + 3 * stride];
        nfloat4 oa, ob, oc, od;
        oa.x = quant1(a.x, s, inv, ee); oa.y = quant1(a.y, s, inv, ee);
        oa.z = quant1(a.z, s, inv, ee); oa.w = quant1(a.w, s, inv, ee);
        __builtin_nontemporal_store(oa, (nfloat4*)&out[base]);
        ob.x = quant1(b.x, s, inv, ee); ob.y = quant1(b.y, s, inv, ee);
        ob.z = quant1(b.z, s, inv, ee); ob.w = quant1(b.w, s, inv, ee);
        __builtin_nontemporal_store(ob, (nfloat4*)&out[base + stride]);
        oc.x = quant1(c.x, s, inv, ee); oc.y = quant1(c.y, s, inv, ee);
        oc.z = quant1(c.z, s, inv, ee); oc.w = quant1(c.w, s, inv, ee);
        __builtin_nontemporal_store(oc, (nfloat4*)&out[base + 2 * stride]);
        od.x = quant1(d.x, s, inv, ee); od.y = quant1(d.y, s, inv, ee);
        od.z = quant1(d.z, s, inv, ee); od.w = quant1(d.w, s, inv, ee);
        __builtin_nontemporal_store(od, (nfloat4*)&out[base + 3 * stride]);
    }
}

extern "C" void kernel_launch(void* const* d_in, const int* in_sizes, int n_in,
                              void* d_out, int out_size, void* d_ws, size_t ws_size,
                              hipStream_t stream) {
    const float* weight    = (const float*)d_in[0];
    const float* eps_param = (const float*)d_in[1];
    const float* delta     = (const float*)d_in[2];
    float* out  = (float*)d_out;
    float* tail = out + TOTAL_ELEMS;            // 1024 floats: eps_eff + e_base
    unsigned int* gmax = (unsigned int*)d_ws;   // 512 uints of scratch

    init_kernel<<<1, NGRP, 0, stream>>>(gmax);
    maxabs_kernel<<<2048, 256, 0, stream>>>((const float4*)weight, gmax);
    // 8192 blocks * 256 threads = 2,097,152 threads; TOTAL4 / threads = 8 iters
    quant_kernel<<<8192, 256, 0, stream>>>((const float4*)weight, eps_param,
                                           delta, gmax, tail, (float4*)out);
}